// Round 11
// baseline (1741.724 us; speedup 1.0000x reference)
//
#include <hip/hip_runtime.h>
#include <hip/hip_bf16.h>

typedef __hip_bfloat16 bf16;
typedef unsigned short u16;
typedef __attribute__((ext_vector_type(8))) short s8v;   // 8 bf16 = 4 VGPR
typedef __attribute__((ext_vector_type(4))) float f4v;   // MFMA accumulator

#define MFMA16(a, b, c) __builtin_amdgcn_mfma_f32_16x16x32_bf16((a), (b), (c), 0, 0, 0)

__device__ __forceinline__ float b2f(bf16 v) { return __bfloat162float(v); }
__device__ __forceinline__ float sigm(float x) { return 1.0f / (1.0f + __expf(-x)); }
__device__ __forceinline__ float u2f(u16 u) {
  union { float f; unsigned int i; } v; v.i = ((unsigned int)u) << 16; return v.f;
}
__device__ __forceinline__ u16 f2u(float f) {
  bf16 b = __float2bfloat16(f);
  union { bf16 b; u16 u; } v; v.b = b; return v.u;
}

// ---------------- small utility kernels ----------------
__global__ __launch_bounds__(256) void k_cast(const float* __restrict__ s,
                                              bf16* __restrict__ d, int n) {
  int i = blockIdx.x * 256 + threadIdx.x;
  if (i < n) d[i] = __float2bfloat16(s[i]);
}

__global__ __launch_bounds__(256) void k_embed(const int* __restrict__ x,
                                               const float* __restrict__ emb,
                                               bf16* __restrict__ h, int N, int H) {
  int idx = blockIdx.x * 256 + threadIdx.x;
  if (idx >= N * H) return;
  int n = idx / H, c = idx - n * H;
  h[idx] = __float2bfloat16(emb[(size_t)x[n] * H + c]);
}

// catA[r][k] = k<H ? h[gidx[r]][k] : bf16(enc[r][k-H])
__global__ __launch_bounds__(256) void k_cat(const bf16* __restrict__ h,
                                             const int* __restrict__ gidx,
                                             const float* __restrict__ enc,
                                             bf16* __restrict__ catA, int BL, int H) {
  int i = blockIdx.x * 256 + threadIdx.x;
  if (i >= BL * 2 * H) return;
  int r = i / (2 * H), k = i - r * 2 * H;
  catA[i] = (k < H) ? h[(size_t)gidx[r] * H + k]
                    : __float2bfloat16(enc[(size_t)r * H + (k - H)]);
}

// ---------------- CSR build (once per call) ----------------
__global__ __launch_bounds__(256) void k_zero_i32(int* __restrict__ p, int n) {
  int i = blockIdx.x * 256 + threadIdx.x;
  if (i < n) p[i] = 0;
}
__global__ __launch_bounds__(256) void k_hist(const int* __restrict__ ei,
                                              int* __restrict__ deg, int E) {
  int e = blockIdx.x * 256 + threadIdx.x;
  if (e < E) atomicAdd(&deg[ei[E + e]], 1);
}
__global__ __launch_bounds__(256) void k_scan(const int* __restrict__ deg,
                                              int* __restrict__ rowptr, int N) {
  __shared__ int csum[257];
  int t = threadIdx.x;
  int CS = (N + 255) / 256;
  int b0 = t * CS, b1 = min(b0 + CS, N);
  int s = 0;
  for (int i = b0; i < b1; i++) s += deg[i];
  csum[t] = s;
  __syncthreads();
  if (t == 0) {
    int run = 0;
    for (int q = 0; q < 256; q++) { int tmp = csum[q]; csum[q] = run; run += tmp; }
    csum[256] = run;
  }
  __syncthreads();
  int run = csum[t];
  for (int i = b0; i < b1; i++) { rowptr[i] = run; run += deg[i]; }
  if (t == 0) rowptr[N] = csum[256];
}
__global__ __launch_bounds__(256) void k_copy_i32(const int* __restrict__ s,
                                                  int* __restrict__ d, int n) {
  int i = blockIdx.x * 256 + threadIdx.x;
  if (i < n) d[i] = s[i];
}
__global__ __launch_bounds__(256) void k_fill(const int* __restrict__ ei,
                                              const float* __restrict__ ew,
                                              int* __restrict__ cursor,
                                              int* __restrict__ srcs,
                                              float* __restrict__ wts, int E) {
  int e = blockIdx.x * 256 + threadIdx.x;
  if (e >= E) return;
  int d = ei[E + e];
  int pos = atomicAdd(&cursor[d], 1);
  srcs[pos] = ei[e];
  wts[pos] = ew[e];
}

// sh[d][:] = sum_e wts[e] * h[srcs[e]][:]
__global__ __launch_bounds__(256) void k_aggregate(const int* __restrict__ rowptr,
                                                   const int* __restrict__ srcs,
                                                   const float* __restrict__ wts,
                                                   const bf16* __restrict__ hsrc,
                                                   bf16* __restrict__ sh,
                                                   int N, int H) {
  int wv = threadIdx.x >> 6, lane = threadIdx.x & 63;
  int d = blockIdx.x * 4 + wv;
  if (d >= N) return;
  int beg = rowptr[d], end = rowptr[d + 1];
  const u16* hp = (const u16*)hsrc;
  for (int c0 = lane * 4; c0 < H; c0 += 256) {
    float a0 = 0.f, a1 = 0.f, a2 = 0.f, a3 = 0.f;
    int i = beg;
    for (; i + 4 <= end; i += 4) {
      int s0 = srcs[i], s1 = srcs[i + 1], s2 = srcs[i + 2], s3 = srcs[i + 3];
      float w0 = wts[i], w1 = wts[i + 1], w2 = wts[i + 2], w3 = wts[i + 3];
      ushort4 r0 = *(const ushort4*)(hp + (size_t)s0 * H + c0);
      ushort4 r1 = *(const ushort4*)(hp + (size_t)s1 * H + c0);
      ushort4 r2 = *(const ushort4*)(hp + (size_t)s2 * H + c0);
      ushort4 r3 = *(const ushort4*)(hp + (size_t)s3 * H + c0);
      a0 += w0 * u2f(r0.x) + w1 * u2f(r1.x) + w2 * u2f(r2.x) + w3 * u2f(r3.x);
      a1 += w0 * u2f(r0.y) + w1 * u2f(r1.y) + w2 * u2f(r2.y) + w3 * u2f(r3.y);
      a2 += w0 * u2f(r0.z) + w1 * u2f(r1.z) + w2 * u2f(r2.z) + w3 * u2f(r3.z);
      a3 += w0 * u2f(r0.w) + w1 * u2f(r1.w) + w2 * u2f(r2.w) + w3 * u2f(r3.w);
    }
    for (; i < end; i++) {
      int s0 = srcs[i];
      float w0 = wts[i];
      ushort4 r0 = *(const ushort4*)(hp + (size_t)s0 * H + c0);
      a0 += w0 * u2f(r0.x); a1 += w0 * u2f(r0.y);
      a2 += w0 * u2f(r0.z); a3 += w0 * u2f(r0.w);
    }
    ushort4 o;
    o.x = f2u(a0); o.y = f2u(a1); o.z = f2u(a2); o.w = f2u(a3);
    *(ushort4*)((u16*)sh + (size_t)d * H + c0) = o;
  }
}

// ---------------- MFMA GEMM: C[M,Nc] = A[M,K] @ Bt[Nc,K]^T ----------------
template <int OUT_F32>
__global__ __launch_bounds__(256) void k_gemm(const bf16* __restrict__ A,
                                              const bf16* __restrict__ Bt,
                                              void* __restrict__ Cv,
                                              const float* __restrict__ bias,
                                              int M, int K, int Nc) {
  __shared__ short As[128][40];
  __shared__ short Bs[64][40];
  int gm = blockIdx.x * 128, gn = blockIdx.y * 64;
  int tid = threadIdx.x, w = tid >> 6, lane = tid & 63;
  int l15 = lane & 15, koff = (lane >> 4) * 8;
  f4v acc[2][4];
#pragma unroll
  for (int i = 0; i < 2; i++)
#pragma unroll
    for (int j = 0; j < 4; j++) acc[i][j] = (f4v)0.f;

  for (int kt = 0; kt < K; kt += 32) {
#pragma unroll
    for (int c = 0; c < 2; c++) {
      int ch = tid + c * 256;
      int row = ch >> 2, seg = ch & 3;
      *(float4*)&As[row][seg * 8] =
          *(const float4*)(A + (size_t)(gm + row) * K + kt + seg * 8);
    }
    {
      int row = tid >> 2, seg = tid & 3;
      *(float4*)&Bs[row][seg * 8] =
          *(const float4*)(Bt + (size_t)(gn + row) * K + kt + seg * 8);
    }
    __syncthreads();
    s8v af[2], bf[4];
#pragma unroll
    for (int rt = 0; rt < 2; rt++) af[rt] = *(const s8v*)&As[w * 32 + rt * 16 + l15][koff];
#pragma unroll
    for (int ct = 0; ct < 4; ct++) bf[ct] = *(const s8v*)&Bs[ct * 16 + l15][koff];
#pragma unroll
    for (int rt = 0; rt < 2; rt++)
#pragma unroll
      for (int ct = 0; ct < 4; ct++) acc[rt][ct] = MFMA16(af[rt], bf[ct], acc[rt][ct]);
    __syncthreads();
  }
#pragma unroll
  for (int rt = 0; rt < 2; rt++)
#pragma unroll
    for (int ct = 0; ct < 4; ct++)
#pragma unroll
      for (int r = 0; r < 4; r++) {
        int row = gm + w * 32 + rt * 16 + (lane >> 4) * 4 + r;
        int col = gn + ct * 16 + l15;
        float v = acc[rt][ct][r];
        if (OUT_F32) ((float*)Cv)[(size_t)row * Nc + col] = v + bias[col];
        else         ((bf16*)Cv)[(size_t)row * Nc + col] = __float2bfloat16(v);
      }
}

// ---------------- fused GRU, LDS-FREE: all MFMA fragments loaded directly ---
// from global as dwordx4 (A-frag = 8 contiguous bf16 at (row)*H+kt+koff; same
// for B rows). No __syncthreads, no LDS -> no barrier drains, no bank
// conflicts; latency hidden by ILP across the 28 independent loads/kt.
// r,z gates chain gi+gh into one accumulator; n keeps separate i/h accs.
__global__ __launch_bounds__(256) void k_gru_mfma(const bf16* __restrict__ Ash,
                                                  const bf16* __restrict__ Ah,
                                                  const bf16* __restrict__ Wi,  // Ucomb_l [3H][H]
                                                  const bf16* __restrict__ Wh,  // w_hh [3H][H]
                                                  const float* __restrict__ bi,
                                                  const float* __restrict__ bh,
                                                  bf16* __restrict__ hn,
                                                  int M, int H) {
  int gcol = blockIdx.x * 64, gm = blockIdx.y * 128;
  int tid = threadIdx.x, w = tid >> 6, lane = tid & 63;
  int l15 = lane & 15, koff = (lane >> 4) * 8;
  int arow = gm + w * 32 + l15;          // wave's A rows: arow, arow+16
  f4v accR[2][4], accZ[2][4], accNi[2][4], accNh[2][4];
#pragma unroll
  for (int rt = 0; rt < 2; rt++)
#pragma unroll
    for (int ct = 0; ct < 4; ct++) {
      accR[rt][ct] = (f4v)0.f; accZ[rt][ct] = (f4v)0.f;
      accNi[rt][ct] = (f4v)0.f; accNh[rt][ct] = (f4v)0.f;
    }

  const bf16* pa0 = Ash + (size_t)arow * H + koff;
  const bf16* pa1 = Ash + (size_t)(arow + 16) * H + koff;
  const bf16* ph0 = Ah + (size_t)arow * H + koff;
  const bf16* ph1 = Ah + (size_t)(arow + 16) * H + koff;
  int brow = gcol + l15;                 // B rows: brow + ct*16, gates at g*H

  for (int kt = 0; kt < H; kt += 32) {
    s8v fa[2], fh[2];
    fa[0] = *(const s8v*)(pa0 + kt);
    fa[1] = *(const s8v*)(pa1 + kt);
    fh[0] = *(const s8v*)(ph0 + kt);
    fh[1] = *(const s8v*)(ph1 + kt);
#pragma unroll
    for (int ct = 0; ct < 4; ct++) {
      size_t bbase = (size_t)(brow + ct * 16) * H + kt + koff;
      s8v bRi = *(const s8v*)(Wi + bbase);
      s8v bZi = *(const s8v*)(Wi + (size_t)H * H + bbase);
      s8v bNi = *(const s8v*)(Wi + (size_t)2 * H * H + bbase);
      s8v bRh = *(const s8v*)(Wh + bbase);
      s8v bZh = *(const s8v*)(Wh + (size_t)H * H + bbase);
      s8v bNh = *(const s8v*)(Wh + (size_t)2 * H * H + bbase);
#pragma unroll
      for (int rt = 0; rt < 2; rt++) {
        accR[rt][ct]  = MFMA16(fa[rt], bRi, accR[rt][ct]);
        accR[rt][ct]  = MFMA16(fh[rt], bRh, accR[rt][ct]);
        accZ[rt][ct]  = MFMA16(fa[rt], bZi, accZ[rt][ct]);
        accZ[rt][ct]  = MFMA16(fh[rt], bZh, accZ[rt][ct]);
        accNi[rt][ct] = MFMA16(fa[rt], bNi, accNi[rt][ct]);
        accNh[rt][ct] = MFMA16(fh[rt], bNh, accNh[rt][ct]);
      }
    }
  }
#pragma unroll
  for (int ct = 0; ct < 4; ct++) {
    int col = gcol + ct * 16 + l15;
    float br  = bi[col] + bh[col];
    float bz  = bi[H + col] + bh[H + col];
    float bin = bi[2 * H + col], bhn = bh[2 * H + col];
#pragma unroll
    for (int rt = 0; rt < 2; rt++)
#pragma unroll
      for (int r = 0; r < 4; r++) {
        int row = gm + w * 32 + rt * 16 + (lane >> 4) * 4 + r;
        float rr = sigm(accR[rt][ct][r] + br);
        float zz = sigm(accZ[rt][ct][r] + bz);
        float nn = tanhf(accNi[rt][ct][r] + bin + rr * (accNh[rt][ct][r] + bhn));
        float hv = b2f(Ah[(size_t)row * H + col]);
        hn[(size_t)row * H + col] = __float2bfloat16((1.f - zz) * nn + zz * hv);
      }
  }
}

static inline size_t alg(size_t x) { return (x + 255) & ~(size_t)255; }
static inline int cdiv(int a, int b) { return (a + b - 1) / b; }

extern "C" void kernel_launch(void* const* d_in, const int* in_sizes, int n_in,
                              void* d_out, int out_size, void* d_ws, size_t ws_size,
                              hipStream_t stream) {
  (void)out_size; (void)ws_size;
  int s = (n_in >= 14) ? 0 : -1;
  const int*   x     = (const int*)d_in[0];
  const int*   ei    = (const int*)d_in[1];
  const float* ew    = (const float*)d_in[2];
  const int*   gidx  = (const int*)d_in[3];
  const float* enc   = (const float*)d_in[5 + s];
  const float* emb   = (const float*)d_in[6 + s];
  const float* ggcw  = (const float*)d_in[7 + s];
  const float* w_ih  = (const float*)d_in[8 + s];
  const float* w_hh  = (const float*)d_in[9 + s];
  const float* b_ih  = (const float*)d_in[10 + s];
  const float* b_hh  = (const float*)d_in[11 + s];
  const float* out_w = (const float*)d_in[12 + s];
  const float* out_b = (const float*)d_in[13 + s];
  float* out = (float*)d_out;

  int N   = in_sizes[0];
  int E   = in_sizes[2];
  int BL  = in_sizes[3];
  int H   = in_sizes[5 + s] / BL;
  int LG  = in_sizes[7 + s] / (H * H);
  int OUT = in_sizes[12 + s] / (2 * H);

  size_t nh = (size_t)N * H;
  size_t hh3 = (size_t)3 * H * H;
  char* p = (char*)d_ws;
  size_t off = 0;
  bf16* wihB  = (bf16*)(p + off); off = alg(off + hh3 * 2);
  bf16* whhB  = (bf16*)(p + off); off = alg(off + hh3 * 2);
  bf16* outwB = (bf16*)(p + off); off = alg(off + (size_t)OUT * 2 * H * 2);
  bf16* ggcwB = (bf16*)(p + off); off = alg(off + (size_t)LG * H * H * 2);
  bf16* Ucomb = (bf16*)(p + off); off = alg(off + (size_t)LG * hh3 * 2);
  bf16* hA    = (bf16*)(p + off); off = alg(off + nh * 2);
  bf16* hB    = (bf16*)(p + off); off = alg(off + nh * 2);
  bf16* shB   = (bf16*)(p + off); off = alg(off + nh * 2);
  bf16* catA  = (bf16*)(p + off); off = alg(off + (size_t)BL * 2 * H * 2);
  int* deg    = (int*)(p + off);  off = alg(off + (size_t)N * 4);
  int* rowptr = (int*)(p + off);  off = alg(off + (size_t)(N + 1) * 4);
  int* cursor = (int*)(p + off);  off = alg(off + (size_t)N * 4);
  int* srcs   = (int*)(p + off);  off = alg(off + (size_t)E * 4);
  float* wts  = (float*)(p + off); off = alg(off + (size_t)E * 4);

  // weight prep
  k_cast<<<cdiv((int)hh3, 256), 256, 0, stream>>>(w_ih, wihB, (int)hh3);
  k_cast<<<cdiv((int)hh3, 256), 256, 0, stream>>>(w_hh, whhB, (int)hh3);
  k_cast<<<cdiv(OUT * 2 * H, 256), 256, 0, stream>>>(out_w, outwB, OUT * 2 * H);
  k_cast<<<cdiv(LG * H * H, 256), 256, 0, stream>>>(ggcw, ggcwB, LG * H * H);
  // Ucomb_l[c][k] = sum_p w_ih[c][p] * ggcw_l[k][p]
  for (int l = 0; l < LG; l++)
    k_gemm<0><<<dim3(3 * H / 128, H / 64), 256, 0, stream>>>(
        wihB, ggcwB + (size_t)l * H * H, Ucomb + (size_t)l * hh3, nullptr, 3 * H, H, H);

  // embedding + CSR build
  k_embed<<<cdiv(N * H, 256), 256, 0, stream>>>(x, emb, hA, N, H);
  k_zero_i32<<<cdiv(N, 256), 256, 0, stream>>>(deg, N);
  k_hist<<<cdiv(E, 256), 256, 0, stream>>>(ei, deg, E);
  k_scan<<<1, 256, 0, stream>>>(deg, rowptr, N);
  k_copy_i32<<<cdiv(N, 256), 256, 0, stream>>>(rowptr, cursor, N);
  k_fill<<<cdiv(E, 256), 256, 0, stream>>>(ei, ew, cursor, srcs, wts, E);

  bf16* h = hA;
  bf16* hn = hB;
  for (int l = 0; l < LG; l++) {
    k_aggregate<<<cdiv(N, 4), 256, 0, stream>>>(rowptr, srcs, wts, h, shB, N, H);
    k_gru_mfma<<<dim3(H / 64, N / 128), 256, 0, stream>>>(
        shB, h, Ucomb + (size_t)l * hh3, whhB, b_ih, b_hh, hn, N, H);
    bf16* t = h; h = hn; hn = t;
  }
  k_cat<<<cdiv(BL * 2 * H, 256), 256, 0, stream>>>(h, gidx, enc, catA, BL, H);
  k_gemm<1><<<dim3(BL / 128, OUT / 64), 256, 0, stream>>>(
      catA, outwB, out, out_b, BL, 2 * H, OUT);
}